// Round 8
// baseline (52.379 us; speedup 1.0000x reference)
//
#include <hip/hip_runtime.h>
#include <math.h>

// Problem constants (from setup_inputs: batch=1024, dim_z=32, n_samples=32, agg_size=256)
#define B    1024
#define D    32
#define NS   32
#define AGG  256
#define NC   (B / AGG)      // 4 chunks
#define M    (AGG * NS)     // 8192 samples per chunk
#define NJB  4              // j-blocks per (c,k)
#define JB   (M / NJB)      // 2048 samples per block
#define TJ   (JB / 256)     // 8 samples per thread
#define NBLK (NC * D * NJB) // 512 blocks -> 2 blocks/CU -> 8 waves/CU
                            // param tables: 2 x 4KB per CU -> fits scalar K$

typedef float v2f __attribute__((ext_vector_type(2)));

// ws layout: [0]: uint counter | @256: float partial[NBLK] (2KB) | @8192: float4 params
// params[(c*D+k)*AGG + i] = {A, B, C, sd}:
//   arg(z) = A*z^2 + B*z + C = -0.5*log2e*((z-mu)^2*exp(-lv) + lv),  sd = exp(0.5*lv)
//   (mu recoverable as -0.5*B/A)
__global__ __launch_bounds__(256) void ksetup(const float* __restrict__ mean,
                                              const float* __restrict__ logvar,
                                              float4* __restrict__ params,
                                              unsigned* __restrict__ counter)
{
    constexpr float LOG2E = 1.4426950408889634f;
    const int tid = blockIdx.x * 256 + threadIdx.x;   // over B*D = 32768, k fastest
    if (tid == 0) counter[0] = 0u;                    // reset last-block counter
    const int row = tid >> 5;        // 0..1023  (global component row)
    const int k   = tid & (D - 1);
    const int c   = row >> 8;
    const int i   = row & (AGG - 1);
    const float mu = mean[tid];      // coalesced
    const float lv = logvar[tid];
    const float ev = __builtin_amdgcn_exp2f(-lv * LOG2E);      // exp(-lv); lv~N(0,1): safe
    params[((c * D + k) << 8) | i] =
        make_float4(-0.5f * LOG2E * ev,
                    LOG2E * mu * ev,
                    -0.5f * LOG2E * fmaf(mu * mu, ev, lv),
                    __builtin_amdgcn_exp2f(0.5f * LOG2E * lv)); // sd = exp(0.5*lv)
}

__global__ __launch_bounds__(256) void kmain(const float* __restrict__ eps,
                                             const float4* __restrict__ params,
                                             float* __restrict__ partial,
                                             unsigned* __restrict__ counter,
                                             float* __restrict__ out)
{
    constexpr float LN2 = 0.6931471805599453f;
    const int bid = blockIdx.x;
    const int c   = bid / (D * NJB);
    const int rem = bid - c * (D * NJB);
    const int k   = rem / NJB;
    const int jb  = rem - k * NJB;
    const int j0  = jb * JB;
    const int t   = threadIdx.x;

    // Block-uniform param table base -> compiler emits batched s_load_dwordx16
    // (scalar path: no VALU issue slots, no LDS pipe, K$-resident at 2 blocks/CU).
    const float4* __restrict__ pk = params + ((c * D + k) << 8);

    // Scattered eps gathers (L2 latency hides under the z-prologue).
    float ev[TJ];
#pragma unroll
    for (int u = 0; u < TJ; ++u)
        ev[u] = eps[(size_t)(c * M + j0 + t + 256 * u) * D + k];

    // z for this thread's TJ samples (z2 flat layout == eps flat layout).
    float zv[TJ];
#pragma unroll
    for (int u = 0; u < TJ; ++u) {
        const float4 p = pk[(t + 256 * u) >> 5];         // own component (uniform per wave-half)
        const float mu = -0.5f * p.y * __builtin_amdgcn_rcpf(p.x);
        zv[u] = fmaf(ev[u], p.w, mu);
    }
    v2f zp[TJ / 2], accv[TJ / 2];
#pragma unroll
    for (int q = 0; q < TJ / 2; ++q) {
        zp[q]   = (v2f){zv[2 * q], zv[2 * q + 1]};
        accv[q] = (v2f){0.f, 0.f};
    }

    // Pairwise loop over 256 components, params via scalar loads (unroll-8 window:
    // 2x s_load_dwordx16 covers 8 components, ~700 cyc of compute hides K$ latency).
    // Per sample-pair: 2 v_pk_fma + 1 v_pk_add (6 cyc) + 2 v_exp (16 cyc).
#pragma unroll 8
    for (int i = 0; i < AGG; ++i) {
        const float4 p = pk[i];
        const v2f A2 = (v2f){p.x, p.x};
        const v2f B2 = (v2f){p.y, p.y};
        const v2f C2 = (v2f){p.z, p.z};
#pragma unroll
        for (int q = 0; q < TJ / 2; ++q) {
            const v2f arg = (A2 * zp[q] + B2) * zp[q] + C2;
            accv[q] += (v2f){__builtin_amdgcn_exp2f(arg.x),
                             __builtin_amdgcn_exp2f(arg.y)};
        }
    }

    // per-thread contribution: ln(sum_i) + 0.5*z^2 (global constants folded at the end)
    float r = 0.f;
#pragma unroll
    for (int q = 0; q < TJ / 2; ++q) {
        r += LN2 * __builtin_amdgcn_logf(accv[q].x) + 0.5f * zp[q].x * zp[q].x;
        r += LN2 * __builtin_amdgcn_logf(accv[q].y) + 0.5f * zp[q].y * zp[q].y;
    }

    // deterministic block reduction
    for (int off = 32; off > 0; off >>= 1) r += __shfl_down(r, off, 64);
    __shared__ float wsum[4];
    if ((t & 63) == 0) wsum[t >> 6] = r;
    __syncthreads();

    // last-block final reduction (deterministic: fixed-order sum over partial[])
    __shared__ int isLast;
    if (t == 0) {
        partial[bid] = (wsum[0] + wsum[1]) + (wsum[2] + wsum[3]);
        __threadfence();                          // publish partial device-wide
        const unsigned old = atomicAdd(counter, 1u);
        isLast = (old == (unsigned)(NBLK - 1));
    }
    __syncthreads();
    if (isLast) {
        __threadfence();                          // acquire all partials
        double s = 0.0;
#pragma unroll
        for (int i = 0; i < NBLK / 256; ++i) s += (double)partial[i * 256 + t];
        __shared__ double sd[256];
        sd[t] = s;
        __syncthreads();
        for (int off = 128; off > 0; off >>= 1) {
            if (t < off) sd[t] += sd[t + off];
            __syncthreads();
        }
        if (t == 0) {
            // out = total/(nc*M) - D*ln(256)
            out[0] = (float)(sd[0] * (1.0 / (double)(NC * M))
                             - (double)D * 5.545177444479562);
        }
    }
}

extern "C" void kernel_launch(void* const* d_in, const int* in_sizes, int n_in,
                              void* d_out, int out_size, void* d_ws, size_t ws_size,
                              hipStream_t stream)
{
    const float* mean   = (const float*)d_in[0];
    const float* logvar = (const float*)d_in[1];
    const float* eps    = (const float*)d_in[2];
    float* out = (float*)d_out;

    unsigned* counter = (unsigned*)d_ws;
    float*    partial = (float*)((char*)d_ws + 256);    // NBLK floats
    float4*   params  = (float4*)((char*)d_ws + 8192);  // 512KB param table

    ksetup<<<(B * D) / 256, 256, 0, stream>>>(mean, logvar, params, counter);
    kmain<<<NBLK, 256, 0, stream>>>(eps, params, partial, counter, out);
}